// Round 7
// baseline (40.628 us; speedup 1.0000x reference)
//
#include <hip/hip_runtime.h>

#define NB 131072
#define NSTEPS 30
// 0.8^30 and 1-0.8^30
#define LAMBDA  1.2379400392853803e-3f
#define ONEMLAM 0.9987620599607146f

typedef float  float4v __attribute__((ext_vector_type(4)));
typedef short  short4v __attribute__((ext_vector_type(4)));

#define MFMA16 __builtin_amdgcn_mfma_f32_16x16x16bf16_1k

static __device__ __forceinline__ unsigned fb(float f) {
    union { float f; unsigned u; } c; c.f = f; return c.u;
}
static __device__ __forceinline__ float fu(unsigned u) {
    union { unsigned u; float f; } c; c.u = u; return c.f;
}

struct bfpair { short4v hi, lo; };

// Truncation split, pure C++: hi = trunc_bf16(v); lo = trunc_bf16(v - hi).
// v = hi + lo + err, |err| <= 2^-16 |v|.
static __device__ __forceinline__ bfpair split4(float4v v) {
    unsigned u0 = fb(v[0]), u1 = fb(v[1]), u2 = fb(v[2]), u3 = fb(v[3]);
    float l0 = v[0] - fu(u0 & 0xffff0000u);
    float l1 = v[1] - fu(u1 & 0xffff0000u);
    float l2 = v[2] - fu(u2 & 0xffff0000u);
    float l3 = v[3] - fu(u3 & 0xffff0000u);
    union { unsigned u[2]; short4v s; } H, L;
    H.u[0] = __builtin_amdgcn_perm(u1, u0, 0x07060302u);       // [hi(v0) | hi(v1)]
    H.u[1] = __builtin_amdgcn_perm(u3, u2, 0x07060302u);
    L.u[0] = __builtin_amdgcn_perm(fb(l1), fb(l0), 0x07060302u);
    L.u[1] = __builtin_amdgcn_perm(fb(l3), fb(l2), 0x07060302u);
    bfpair P; P.hi = H.s; P.lo = L.s; return P;
}

// hi-only truncation pack: 2 VALU per 4 values
static __device__ __forceinline__ short4v pack_hi4(float4v v) {
    union { unsigned u[2]; short4v s; } H;
    H.u[0] = __builtin_amdgcn_perm(fb(v[1]), fb(v[0]), 0x07060302u);
    H.u[1] = __builtin_amdgcn_perm(fb(v[3]), fb(v[2]), 0x07060302u);
    return H.s;
}

static __device__ __forceinline__ float sigmoid_f(float p) {
    return __builtin_amdgcn_rcpf(1.0f + __expf(-p));
}

__global__ __launch_bounds__(256, 6) void pcnet_kernel(
    const float* __restrict__ x,    // [B,16]
    const float* __restrict__ W1,   // [64,16]
    const float* __restrict__ b1,   // [64]
    const float* __restrict__ W2,   // [16,64]
    const float* __restrict__ b2,   // [16]
    const float* __restrict__ x1i,  // [B,64]
    const float* __restrict__ x2i,  // [B,16]
    float* __restrict__ out)        // [B,64] x1 then [B,16] x2
{
    const int tid  = blockIdx.x * 256 + threadIdx.x;
    const int wave = tid >> 6;
    const int lane = threadIdx.x & 63;
    const int g = lane >> 4;          // lane group 0..3
    const int q = lane & 15;          // 16x16 row/col index
    const int r = wave * 16 + q;      // batch row handled by this lane

    // ---- W2 split fragments (A-operand: A[q][4g+j] = W2[q][16c+4g+j]) ----
    bfpair a_w2[4];
#pragma unroll
    for (int c = 0; c < 4; ++c) {
        float4v w = *(const float4v*)(W2 + q * 64 + 16 * c + 4 * g);
        a_w2[c] = split4(w);
    }
    const float4v b2f = *(const float4v*)(b2 + 4 * g);   // b2[4g+j] (C-row layout)
    const float4v zero4 = {0.f, 0.f, 0.f, 0.f};

    // ---- mu1 = sigmoid(x @ W1^T + b1); immediately fold into epilogue state:
    //      x1c = lambda*x1_0 + (1-lambda)*mu1  (also keep mu1 transiently for c1)
    float4v xv = *(const float4v*)(x + r * 16 + 4 * g);
    bfpair bx = split4(xv);
    float4v x1c[4];     // loop-live epilogue state
    float4v mu1v[4];    // transient (dead after c1)
#pragma unroll
    for (int t = 0; t < 4; ++t) {
        float4v aw = *(const float4v*)(W1 + (16 * t + q) * 16 + 4 * g);
        bfpair a1 = split4(aw);
        float4v acc = *(const float4v*)(b1 + 16 * t + 4 * g);
        acc = MFMA16(a1.hi, bx.hi, acc, 0, 0, 0);
        acc = MFMA16(a1.hi, bx.lo, acc, 0, 0, 0);
        acc = MFMA16(a1.lo, bx.hi, acc, 0, 0, 0);
        float4v x10 = *(const float4v*)(x1i + r * 64 + 16 * t + 4 * g);
#pragma unroll
        for (int j = 0; j < 4; ++j) {
            float m = sigmoid_f(acc[j]);
            mu1v[t][j] = m;
            x1c[t][j] = fmaf(LAMBDA, x10[j], ONEMLAM * m);
        }
    }

    // ---- p0 = W2 @ x1_0 + b2  and  c1 = W2 @ mu1 : 3 parallel chains each ----
    float4v pa = b2f, pb = zero4, pc = zero4;          // p0 chains
    float4v ca = zero4, cb = zero4, cc = zero4;        // c1 chains
#pragma unroll
    for (int c = 0; c < 4; ++c) {
        float4v x10 = *(const float4v*)(x1i + r * 64 + 16 * c + 4 * g);
        bfpair b1s = split4(x10);
        pa = MFMA16(a_w2[c].hi, b1s.hi, pa, 0, 0, 0);
        pb = MFMA16(a_w2[c].hi, b1s.lo, pb, 0, 0, 0);
        pc = MFMA16(a_w2[c].lo, b1s.hi, pc, 0, 0, 0);
        bfpair bm = split4(mu1v[c]);
        ca = MFMA16(a_w2[c].hi, bm.hi, ca, 0, 0, 0);
        cb = MFMA16(a_w2[c].hi, bm.lo, cb, 0, 0, 0);
        cc = MFMA16(a_w2[c].lo, bm.hi, cc, 0, 0, 0);
    }
    float4v pv = (pa + pb) + pc;
    float4v c1 = (ca + cb) + cc;
    float4v qv;
#pragma unroll
    for (int j = 0; j < 4; ++j) qv[j] = 0.2f * (b2f[j] + c1[j]);

    // ---- M_hat = 0.2 * (W2 @ W2^T), hi-only fragment (symmetric: C-layout == A-frag)
    float4v Ma = zero4, Mb = zero4, Mc = zero4;
#pragma unroll
    for (int c = 0; c < 4; ++c) {
        Ma = MFMA16(a_w2[c].hi, a_w2[c].hi, Ma, 0, 0, 0);
        Mb = MFMA16(a_w2[c].hi, a_w2[c].lo, Mb, 0, 0, 0);
        Mc = MFMA16(a_w2[c].lo, a_w2[c].hi, Mc, 0, 0, 0);
    }
    short4v mfr = pack_hi4(0.2f * ((Ma + Mb) + Mc));

    // ---- state: p (16-dim projection), x2, S = sum 0.8^k d ----
    float4v x2v = *(const float4v*)(x2i + r * 16 + 4 * g);
    float4v Sv = zero4;

    // ---- 30 steps in 16-dim space: 1 MFMA + ~25 VALU + 8 trans per step ----
#pragma unroll 1
    for (int s = 0; s < NSTEPS; ++s) {
        float4v dv;
#pragma unroll
        for (int j = 0; j < 4; ++j) {
            float mu2 = sigmoid_f(pv[j]);
            float e2  = x2v[j] - mu2;
            float mm  = fmaf(-mu2, mu2, mu2);          // mu2*(1-mu2)
            dv[j]  = e2 * mm;
            x2v[j] = fmaf(-0.2f, e2, x2v[j]);          // x2' = x2 - 0.2 e2
            Sv[j]  = fmaf(0.8f, Sv[j], dv[j]);         // S' = 0.8 S + d
        }
        short4v bd = pack_hi4(dv);
        float4v pn;
#pragma unroll
        for (int j = 0; j < 4; ++j) pn[j] = fmaf(0.8f, pv[j], qv[j]);
        pv = MFMA16(mfr, bd, pn, 0, 0, 0);
    }

    // ---- epilogue: x1_N = x1c + 0.2*W2^T @ S ----
    short4v bs = pack_hi4(Sv);
#pragma unroll
    for (int t = 0; t < 4; ++t) {
        float4v e;
        e[0] = 0.2f * W2[(4 * g + 0) * 64 + 16 * t + q];
        e[1] = 0.2f * W2[(4 * g + 1) * 64 + 16 * t + q];
        e[2] = 0.2f * W2[(4 * g + 2) * 64 + 16 * t + q];
        e[3] = 0.2f * W2[(4 * g + 3) * 64 + 16 * t + q];
        bfpair a_ep = split4(e);
        float4v acc = x1c[t];
        acc = MFMA16(a_ep.hi, bs, acc, 0, 0, 0);
        acc = MFMA16(a_ep.lo, bs, acc, 0, 0, 0);
        *(float4v*)(out + r * 64 + 16 * t + 4 * g) = acc;
    }
    *(float4v*)(out + (size_t)NB * 64 + r * 16 + 4 * g) = x2v;
}

extern "C" void kernel_launch(void* const* d_in, const int* in_sizes, int n_in,
                              void* d_out, int out_size, void* d_ws, size_t ws_size,
                              hipStream_t stream) {
    const float* x   = (const float*)d_in[0];
    const float* W1  = (const float*)d_in[1];
    const float* b1  = (const float*)d_in[2];
    const float* W2  = (const float*)d_in[3];
    const float* b2  = (const float*)d_in[4];
    const float* x1i = (const float*)d_in[5];
    const float* x2i = (const float*)d_in[6];
    float* out = (float*)d_out;

    dim3 grid(NB / 64);   // 16 rows per wave, 4 waves per block
    dim3 block(256);
    pcnet_kernel<<<grid, block, 0, stream>>>(x, W1, b1, W2, b2, x1i, x2i, out);
}

// Round 8
// 33.616 us; speedup vs baseline: 1.2086x; 1.2086x over previous
//
#include <hip/hip_runtime.h>

#define NB 131072
#define NSTEPS 30
// 0.8^30 and 1-0.8^30
#define LAMBDA  1.2379400392853803e-3f
#define ONEMLAM 0.9987620599607146f

typedef float  float4v __attribute__((ext_vector_type(4)));
typedef short  short4v __attribute__((ext_vector_type(4)));

#define MFMA16 __builtin_amdgcn_mfma_f32_16x16x16bf16_1k

static __device__ __forceinline__ unsigned fb(float f) {
    union { float f; unsigned u; } c; c.f = f; return c.u;
}
static __device__ __forceinline__ float fu(unsigned u) {
    union { unsigned u; float f; } c; c.u = u; return c.f;
}

struct bfpair { short4v hi, lo; };

// Truncation split, pure C++: hi = trunc_bf16(v); lo = trunc_bf16(v - hi).
// v = hi + lo + err, |err| <= 2^-16 |v|.
static __device__ __forceinline__ bfpair split4(float4v v) {
    unsigned u0 = fb(v[0]), u1 = fb(v[1]), u2 = fb(v[2]), u3 = fb(v[3]);
    float l0 = v[0] - fu(u0 & 0xffff0000u);
    float l1 = v[1] - fu(u1 & 0xffff0000u);
    float l2 = v[2] - fu(u2 & 0xffff0000u);
    float l3 = v[3] - fu(u3 & 0xffff0000u);
    union { unsigned u[2]; short4v s; } H, L;
    H.u[0] = __builtin_amdgcn_perm(u1, u0, 0x07060302u);       // [hi(v0) | hi(v1)]
    H.u[1] = __builtin_amdgcn_perm(u3, u2, 0x07060302u);
    L.u[0] = __builtin_amdgcn_perm(fb(l1), fb(l0), 0x07060302u);
    L.u[1] = __builtin_amdgcn_perm(fb(l3), fb(l2), 0x07060302u);
    bfpair P; P.hi = H.s; P.lo = L.s; return P;
}

// hi-only truncation pack: 2 VALU per 4 values
static __device__ __forceinline__ short4v pack_hi4(float4v v) {
    union { unsigned u[2]; short4v s; } H;
    H.u[0] = __builtin_amdgcn_perm(fb(v[1]), fb(v[0]), 0x07060302u);
    H.u[1] = __builtin_amdgcn_perm(fb(v[3]), fb(v[2]), 0x07060302u);
    return H.s;
}

static __device__ __forceinline__ float sigmoid_f(float p) {
    return __builtin_amdgcn_rcpf(1.0f + __expf(-p));
}

__global__ __launch_bounds__(256, 3) void pcnet_kernel(
    const float* __restrict__ x,    // [B,16]
    const float* __restrict__ W1,   // [64,16]
    const float* __restrict__ b1,   // [64]
    const float* __restrict__ W2,   // [16,64]
    const float* __restrict__ b2,   // [16]
    const float* __restrict__ x1i,  // [B,64]
    const float* __restrict__ x2i,  // [B,16]
    float* __restrict__ out)        // [B,64] x1 then [B,16] x2
{
    const int tid  = blockIdx.x * 256 + threadIdx.x;
    const int wave = tid >> 6;
    const int lane = threadIdx.x & 63;
    const int g = lane >> 4;          // lane group 0..3
    const int q = lane & 15;          // 16x16 row/col index
    // two independent row groups per wave (ILP=2)
    int rr[2];
    rr[0] = wave * 32 + q;
    rr[1] = rr[0] + 16;

    // ---- W2 A-frags (shared): A[q][4g+j] = W2[q][16c+4g+j], split hi/lo ----
    bfpair a_w2[4];
#pragma unroll
    for (int c = 0; c < 4; ++c) {
        float4v w = *(const float4v*)(W2 + q * 64 + 16 * c + 4 * g);
        a_w2[c] = split4(w);
    }
    const float4v b2f = *(const float4v*)(b2 + 4 * g);
    const float4v zero4 = {0.f, 0.f, 0.f, 0.f};

    // ---- x per group ----
    bfpair bx[2];
#pragma unroll
    for (int i = 0; i < 2; ++i)
        bx[i] = split4(*(const float4v*)(x + rr[i] * 16 + 4 * g));

    // ---- fused setup: per t-chunk compute mu1, fold x1c, accumulate p0 & c1 ----
    float4v x1c[2][4];                 // lambda*x1_0 + (1-lambda)*mu1
    float4v pacc[2], cacc[2];          // p0 = W2@x1_0 + b2 ; c1 = W2@mu1
#pragma unroll
    for (int i = 0; i < 2; ++i) { pacc[i] = b2f; cacc[i] = zero4; }
#pragma unroll
    for (int t = 0; t < 4; ++t) {
        float4v aw = *(const float4v*)(W1 + (16 * t + q) * 16 + 4 * g);
        bfpair a1 = split4(aw);                           // shared across groups
        float4v binit = *(const float4v*)(b1 + 16 * t + 4 * g);
#pragma unroll
        for (int i = 0; i < 2; ++i) {
            float4v acc = binit;
            acc = MFMA16(a1.hi, bx[i].hi, acc, 0, 0, 0);
            acc = MFMA16(a1.hi, bx[i].lo, acc, 0, 0, 0);
            acc = MFMA16(a1.lo, bx[i].hi, acc, 0, 0, 0);
            float4v x10 = *(const float4v*)(x1i + rr[i] * 64 + 16 * t + 4 * g);
            float4v m;
#pragma unroll
            for (int j = 0; j < 4; ++j) m[j] = sigmoid_f(acc[j]);
#pragma unroll
            for (int j = 0; j < 4; ++j)
                x1c[i][t][j] = fmaf(LAMBDA, x10[j], ONEMLAM * m[j]);
            bfpair b1s = split4(x10);                     // consumed immediately
            bfpair bm  = split4(m);
            pacc[i] = MFMA16(a_w2[t].hi, b1s.hi, pacc[i], 0, 0, 0);
            pacc[i] = MFMA16(a_w2[t].hi, b1s.lo, pacc[i], 0, 0, 0);
            pacc[i] = MFMA16(a_w2[t].lo, b1s.hi, pacc[i], 0, 0, 0);
            cacc[i] = MFMA16(a_w2[t].hi, bm.hi,  cacc[i], 0, 0, 0);
            cacc[i] = MFMA16(a_w2[t].hi, bm.lo,  cacc[i], 0, 0, 0);
            cacc[i] = MFMA16(a_w2[t].lo, bm.hi,  cacc[i], 0, 0, 0);
        }
    }
    float4v pv[2], qv[2];
#pragma unroll
    for (int i = 0; i < 2; ++i) {
        pv[i] = pacc[i];
#pragma unroll
        for (int j = 0; j < 4; ++j) qv[i][j] = 0.2f * (b2f[j] + cacc[i][j]);
    }

    // ---- M_hat = 0.2*(W2 @ W2^T), hi-only frag (symmetric: C-layout == A-frag) ----
    float4v Ma = zero4, Mb = zero4, Mc = zero4;
#pragma unroll
    for (int c = 0; c < 4; ++c) {
        Ma = MFMA16(a_w2[c].hi, a_w2[c].hi, Ma, 0, 0, 0);
        Mb = MFMA16(a_w2[c].hi, a_w2[c].lo, Mb, 0, 0, 0);
        Mc = MFMA16(a_w2[c].lo, a_w2[c].hi, Mc, 0, 0, 0);
    }
    short4v mfr = pack_hi4(0.2f * ((Ma + Mb) + Mc));

    // ---- state: p (16-dim projection), x2, S = sum 0.8^k d ----
    float4v x2v[2], Sv[2];
#pragma unroll
    for (int i = 0; i < 2; ++i) {
        x2v[i] = *(const float4v*)(x2i + rr[i] * 16 + 4 * g);
        Sv[i] = zero4;
    }

    // ---- 30 steps, two independent 16-dim chains interleaved ----
#pragma unroll 1
    for (int s = 0; s < NSTEPS; ++s) {
#pragma unroll
        for (int i = 0; i < 2; ++i) {
            float4v dv;
#pragma unroll
            for (int j = 0; j < 4; ++j) {
                float mu2 = sigmoid_f(pv[i][j]);
                float e2  = x2v[i][j] - mu2;
                float mm  = fmaf(-mu2, mu2, mu2);            // mu2*(1-mu2)
                dv[j]  = e2 * mm;
                x2v[i][j] = fmaf(-0.2f, e2, x2v[i][j]);      // x2' = x2 - 0.2 e2
                Sv[i][j]  = fmaf(0.8f, Sv[i][j], dv[j]);     // S' = 0.8 S + d
            }
            short4v bd = pack_hi4(dv);
            float4v pn;
#pragma unroll
            for (int j = 0; j < 4; ++j) pn[j] = fmaf(0.8f, pv[i][j], qv[i][j]);
            pv[i] = MFMA16(mfr, bd, pn, 0, 0, 0);
        }
    }

    // ---- epilogue: x1_N = x1c + 0.2*W2^T @ S ; A-frag shared across groups ----
    short4v bs[2];
#pragma unroll
    for (int i = 0; i < 2; ++i) bs[i] = pack_hi4(Sv[i]);
#pragma unroll
    for (int t = 0; t < 4; ++t) {
        float4v e;
        e[0] = 0.2f * W2[(4 * g + 0) * 64 + 16 * t + q];
        e[1] = 0.2f * W2[(4 * g + 1) * 64 + 16 * t + q];
        e[2] = 0.2f * W2[(4 * g + 2) * 64 + 16 * t + q];
        e[3] = 0.2f * W2[(4 * g + 3) * 64 + 16 * t + q];
        bfpair a_ep = split4(e);
#pragma unroll
        for (int i = 0; i < 2; ++i) {
            float4v acc = x1c[i][t];
            acc = MFMA16(a_ep.hi, bs[i], acc, 0, 0, 0);
            acc = MFMA16(a_ep.lo, bs[i], acc, 0, 0, 0);
            *(float4v*)(out + rr[i] * 64 + 16 * t + 4 * g) = acc;
        }
    }
#pragma unroll
    for (int i = 0; i < 2; ++i)
        *(float4v*)(out + (size_t)NB * 64 + rr[i] * 16 + 4 * g) = x2v[i];
}

extern "C" void kernel_launch(void* const* d_in, const int* in_sizes, int n_in,
                              void* d_out, int out_size, void* d_ws, size_t ws_size,
                              hipStream_t stream) {
    const float* x   = (const float*)d_in[0];
    const float* W1  = (const float*)d_in[1];
    const float* b1  = (const float*)d_in[2];
    const float* W2  = (const float*)d_in[3];
    const float* b2  = (const float*)d_in[4];
    const float* x1i = (const float*)d_in[5];
    const float* x2i = (const float*)d_in[6];
    float* out = (float*)d_out;

    dim3 grid(NB / 128);   // 32 rows per wave, 4 waves per block
    dim3 block(256);
    pcnet_kernel<<<grid, block, 0, stream>>>(x, W1, b1, W2, b2, x1i, x2i, out);
}